// Round 5
// baseline (431.471 us; speedup 1.0000x reference)
//
#include <hip/hip_runtime.h>

#define S_LEN 2048
#define E_DIM 1024
#define H_NUM 16

typedef __attribute__((ext_vector_type(8))) short s16x8;
typedef __attribute__((ext_vector_type(4))) float f32x4;
typedef __attribute__((ext_vector_type(4))) _Float16 h16x4;

#define GA(p) ((__attribute__((address_space(1))) void*)(p))
#define LA(p) ((__attribute__((address_space(3))) void*)(p))

#define LOG2E 1.4426950408889634f
#define SCALE_Q (0.125f * LOG2E)
#define SHIFT 12.0f   // folded into QK accumulator init; cancels in p/l

union cvt16 { int4 v; s16x8 s8; short e[8]; };

__device__ __forceinline__ short f2bf(float f) {  // RNE
  union { float f; unsigned u; } v; v.f = f;
  unsigned r = v.u + 0x7FFFu + ((v.u >> 16) & 1u);
  return (short)(r >> 16);
}
__device__ __forceinline__ short f2bf_fast(float f) {  // round-half-up (p >= 0)
  union { float f; unsigned u; } v; v.f = f;
  return (short)((v.u + 0x8000u) >> 16);
}

// ---------------------------------------------------------------------------
// Generic transpose + cast + scale: src fp32 (R x C) -> dst bf16 (C x R).
// ---------------------------------------------------------------------------
__global__ void transpose_cast(const float* __restrict__ src, short* __restrict__ dst,
                               int R, int C, long sbs, long dbs, float scale) {
  __shared__ float tile[32][33];
  const float* s = src + (long)blockIdx.z * sbs;
  short* d = dst + (long)blockIdx.z * dbs;
  int c0 = blockIdx.x * 32, r0 = blockIdx.y * 32;
  #pragma unroll
  for (int i = threadIdx.y; i < 32; i += 8)
    tile[i][threadIdx.x] = s[(long)(r0 + i) * C + c0 + threadIdx.x];
  __syncthreads();
  #pragma unroll
  for (int i = threadIdx.y; i < 32; i += 8)
    d[(long)(c0 + i) * R + r0 + threadIdx.x] = f2bf(tile[threadIdx.x][i] * scale);
}

// ---------------------------------------------------------------------------
// All three QKV weights transposed in one launch. z = weight*16 + head.
// Wq gets the log2e/8 score scale folded in.
// ---------------------------------------------------------------------------
__global__ void transpose_qkv(const float* __restrict__ Wq, const float* __restrict__ Wk,
                              const float* __restrict__ Wv, short* __restrict__ dst) {
  __shared__ float tile[32][33];
  const int sel = blockIdx.z >> 4, zz = blockIdx.z & 15;
  const float* s = ((sel == 0) ? Wq : (sel == 1) ? Wk : Wv) + (long)zz * 65536;
  short* d = dst + (long)sel * 1048576 + (long)zz * 65536;
  const float scale = (sel == 0) ? SCALE_Q : 1.0f;
  int c0 = blockIdx.x * 32, r0 = blockIdx.y * 32;
  #pragma unroll
  for (int i = threadIdx.y; i < 32; i += 8)
    tile[i][threadIdx.x] = s[(long)(r0 + i) * 64 + c0 + threadIdx.x];
  __syncthreads();
  #pragma unroll
  for (int i = threadIdx.y; i < 32; i += 8)
    d[(long)(c0 + i) * 1024 + r0 + threadIdx.x] = f2bf(tile[threadIdx.x][i] * scale);
}

// ---------------------------------------------------------------------------
// Plain elementwise bias cast fp32 -> fp16, pre-scaled by log2e.
// ---------------------------------------------------------------------------
__global__ void bias_cast(const float* __restrict__ bias, _Float16* __restrict__ dst) {
  long i = ((long)blockIdx.x * 256 + threadIdx.x) * 4;
  float4 f = *(const float4*)(bias + i);
  h16x4 h;
  h[0] = (_Float16)(f.x * LOG2E); h[1] = (_Float16)(f.y * LOG2E);
  h[2] = (_Float16)(f.z * LOG2E); h[3] = (_Float16)(f.w * LOG2E);
  *(h16x4*)(dst + i) = h;
}

// ---------------------------------------------------------------------------
// QKV projection GEMM, fp32-A direct DMA staging (unchanged from R4).
// ---------------------------------------------------------------------------
__global__ __launch_bounds__(256, 3) void proj_gemm(
    const float* __restrict__ Aq, const float* __restrict__ Ak, const float* __restrict__ Av,
    const short* __restrict__ Bt,
    const float* __restrict__ bq, const float* __restrict__ bk, const float* __restrict__ bv,
    short* __restrict__ qkOut, short* __restrict__ VT) {
  __shared__ float Asub[128 * 64];   // 32 KB, fp32, swizzled 16B chunks
  __shared__ short Bsub[128 * 64];   // 16 KB, bf16, swizzled 16B chunks
  const int tid = threadIdx.x;
  const int w = tid >> 6, lane = tid & 63, ln = lane & 15, quad = lane >> 4;
  const int row0 = blockIdx.x * 128, n0 = blockIdx.y * 128;
  const int seg = n0 >> 10;
  const float* A = (seg == 0) ? Aq : ((seg == 1) ? Ak : Av);
  const float* bptr = (seg == 0) ? bq : ((seg == 1) ? bk : bv);
  const float bscale = (seg == 0) ? SCALE_Q : 1.0f;
  const int nloc = n0 & 1023;
  const int wm = (w & 1) * 64, wn = (w >> 1) * 64;

  f32x4 acc[4][4];
  #pragma unroll
  for (int i = 0; i < 4; ++i)
    #pragma unroll
    for (int j = 0; j < 4; ++j) acc[i][j] = (f32x4){0.f, 0.f, 0.f, 0.f};

  for (int kt = 0; kt < 16; ++kt) {
    const int k0 = kt * 64;
    #pragma unroll
    for (int j = 0; j < 4; ++j) {
      int ci = (w * 4 + j) * 64 + lane;
      int r = ci >> 3, s = ci & 7, g = s ^ (r & 7);
      const short* gb = Bt + (long)(n0 + r) * 1024 + k0 + g * 8;
      __builtin_amdgcn_global_load_lds(GA(gb), LA(&Bsub[ci * 8]), 16, 0, 0);
    }
    #pragma unroll
    for (int it = 0; it < 8; ++it) {
      int ci = it * 256 + tid;
      int r = ci >> 4, s = ci & 15, g = (s & 8) | ((s & 7) ^ (r & 7));
      const float* ga = A + (long)(row0 + r) * 1024 + k0 + g * 4;
      __builtin_amdgcn_global_load_lds(GA(ga), LA(&Asub[ci * 4]), 16, 0, 0);
    }
    __syncthreads();
    #pragma unroll
    for (int kk = 0; kk < 2; ++kk) {
      s16x8 af[4], bfr[4];
      #pragma unroll
      for (int i = 0; i < 4; ++i) {
        int ra = wm + i * 16 + ln;
        int c0 = kk * 8 + quad * 2;
        int s0 = (c0 & 8) | ((c0 & 7) ^ (ra & 7));
        int c1 = c0 + 1;
        int s1 = (c1 & 8) | ((c1 & 7) ^ (ra & 7));
        f32x4 lo = *(const f32x4*)&Asub[ra * 64 + s0 * 4];
        f32x4 hi = *(const f32x4*)&Asub[ra * 64 + s1 * 4];
        s16x8 t;
        t[0] = f2bf(lo[0]); t[1] = f2bf(lo[1]); t[2] = f2bf(lo[2]); t[3] = f2bf(lo[3]);
        t[4] = f2bf(hi[0]); t[5] = f2bf(hi[1]); t[6] = f2bf(hi[2]); t[7] = f2bf(hi[3]);
        af[i] = t;
      }
      #pragma unroll
      for (int j = 0; j < 4; ++j) {
        int rb = wn + j * 16 + ln;
        int slot = (kk * 4 + quad) ^ (rb & 7);
        bfr[j] = *(const s16x8*)&Bsub[rb * 64 + slot * 8];
      }
      #pragma unroll
      for (int i = 0; i < 4; ++i)
        #pragma unroll
        for (int j = 0; j < 4; ++j)
          acc[i][j] = __builtin_amdgcn_mfma_f32_16x16x32_bf16(af[i], bfr[j], acc[i][j], 0, 0, 0);
    }
    __syncthreads();
  }
  if (seg < 2) {
    #pragma unroll
    for (int j = 0; j < 4; ++j) {
      float bvj = bptr[nloc + wn + j * 16 + ln] * bscale;
      int n = n0 + wn + j * 16 + ln;
      #pragma unroll
      for (int i = 0; i < 4; ++i)
        #pragma unroll
        for (int r = 0; r < 4; ++r) {
          int row = row0 + wm + i * 16 + quad * 4 + r;
          qkOut[(long)row * 2048 + n] = f2bf(acc[i][j][r] + bvj);
        }
    }
  } else {
    #pragma unroll
    for (int j = 0; j < 4; ++j) {
      int nl = nloc + wn + j * 16 + ln;
      int hh = nl >> 6, d = nl & 63;
      float bvj = bptr[nl];
      #pragma unroll
      for (int i = 0; i < 4; ++i) {
        int row = row0 + wm + i * 16 + quad * 4;
        int b = row >> 11, t = row & 2047;
        short4 sv;
        sv.x = f2bf(acc[i][j][0] + bvj);
        sv.y = f2bf(acc[i][j][1] + bvj);
        sv.z = f2bf(acc[i][j][2] + bvj);
        sv.w = f2bf(acc[i][j][3] + bvj);
        *(short4*)&VT[((long)(b * 16 + hh) * 64 + d) * 2048 + t] = sv;
      }
    }
  }
}

// ---------------------------------------------------------------------------
// Flash attention, S^T formulation: scores computed as K.Q^T so the C-layout
// gives each lane 4 consecutive t per reg quad -> P stores are ds_write_b64
// (8/iter instead of 32 scalar b16). Shift-softmax, double-buffered DMA,
// XOR-swizzled LDS, fp16 bias (pre-scaled by log2e). Grid (S/128, H, B).
// ---------------------------------------------------------------------------
__global__ __launch_bounds__(256, 3) void flash_attn(
    const short* __restrict__ qk, const short* __restrict__ VT,
    const _Float16* __restrict__ biasF16, short* __restrict__ concat) {
  __shared__ short Ks[2][4096];   // (t, d) xor-swizzled 16B chunks
  __shared__ short Vs[2][4096];   // (d, t) xor-swizzled 16B chunks
  __shared__ short Ps[128 * 72];  // (qrow, t) pad 72 (2-way bank alias = free)
  const int tid = threadIdx.x;
  const int w = tid >> 6, lane = tid & 63, ln = lane & 15, quad = lane >> 4;
  const int q0 = blockIdx.x * 128;
  const int h = blockIdx.y, bb = blockIdx.z;

  // Q fragments (pre-scaled by log2e/8 at prep); B-operand layout for K.Q^T
  s16x8 qf[2][2];
  const short* qbase = qk + (long)(bb * 2048 + q0 + w * 32) * 2048 + h * 64;
  #pragma unroll
  for (int i = 0; i < 2; ++i)
    #pragma unroll
    for (int kk = 0; kk < 2; ++kk) {
      cvt16 u; u.v = *(const int4*)(qbase + (long)(i * 16 + ln) * 2048 + kk * 32 + quad * 8);
      qf[i][kk] = u.s8;
    }

  f32x4 o[2][4];
  float l_st[2] = {0.f, 0.f};   // l for q-row i*16+ln (replicated across quads)
  #pragma unroll
  for (int i = 0; i < 2; ++i)
    #pragma unroll
    for (int nt = 0; nt < 4; ++nt) o[i][nt] = (f32x4){0.f, 0.f, 0.f, 0.f};

  const short* kbase = qk + (long)bb * 2048 * 2048 + 1024 + h * 64;
  const short* vbase = VT + (long)(bb * 16 + h) * 64 * 2048;
  const _Float16* bbase = biasF16 + (long)(q0 + w * 32) * 2048;

  // stage kv=0 into buffer 0
  #pragma unroll
  for (int j = 0; j < 2; ++j) {
    int ci = (w * 2 + j) * 64 + lane;
    int r = ci >> 3, cs = (ci & 7) ^ (r & 7);
    __builtin_amdgcn_global_load_lds(GA(kbase + (long)r * 2048 + cs * 8), LA(&Ks[0][(w * 2 + j) * 512]), 16, 0, 0);
    __builtin_amdgcn_global_load_lds(GA(vbase + (long)r * 2048 + cs * 8), LA(&Vs[0][(w * 2 + j) * 512]), 16, 0, 0);
  }

  for (int kv = 0; kv < 32; ++kv) {
    const int t0 = kv * 64, b = kv & 1;
    __syncthreads();  // own DMA drained pre-barrier -> buf b ready, buf b^1 free

    // bias loads (fp16, *log2e, contiguous 8B): element r -> t = t0+ta*16+quad*4+r
    h16x4 bld[2][4];
    #pragma unroll
    for (int i = 0; i < 2; ++i)
      #pragma unroll
      for (int ta = 0; ta < 4; ++ta)
        bld[i][ta] = *(const h16x4*)(bbase + (long)(i * 16 + ln) * 2048 + t0 + ta * 16 + quad * 4);
    __builtin_amdgcn_sched_barrier(0);

    if (kv < 31) {  // prefetch kv+1 into other buffer
      const short* kb = kbase + (long)(t0 + 64) * 2048;
      const short* vb = vbase + (t0 + 64);
      #pragma unroll
      for (int j = 0; j < 2; ++j) {
        int ci = (w * 2 + j) * 64 + lane;
        int r = ci >> 3, cs = (ci & 7) ^ (r & 7);
        __builtin_amdgcn_global_load_lds(GA(kb + (long)r * 2048 + cs * 8), LA(&Ks[b ^ 1][(w * 2 + j) * 512]), 16, 0, 0);
        __builtin_amdgcn_global_load_lds(GA(vb + (long)r * 2048 + cs * 8), LA(&Vs[b ^ 1][(w * 2 + j) * 512]), 16, 0, 0);
      }
    }

    // S^T = K.Q^T (log2 domain, pre-shifted). C-layout: col=ln -> q, row=quad*4+r -> t
    f32x4 st[4][2];
    #pragma unroll
    for (int ta = 0; ta < 4; ++ta)
      #pragma unroll
      for (int i = 0; i < 2; ++i) st[ta][i] = (f32x4){-SHIFT, -SHIFT, -SHIFT, -SHIFT};
    #pragma unroll
    for (int kk = 0; kk < 2; ++kk) {
      s16x8 kfr[4];
      #pragma unroll
      for (int ta = 0; ta < 4; ++ta)
        kfr[ta] = *(const s16x8*)&Ks[b][((ta * 16 + ln) << 6) + (((kk * 4 + quad) ^ (ln & 7)) << 3)];
      #pragma unroll
      for (int ta = 0; ta < 4; ++ta)
        #pragma unroll
        for (int i = 0; i < 2; ++i)
          st[ta][i] = __builtin_amdgcn_mfma_f32_16x16x32_bf16(kfr[ta], qf[i][kk], st[ta][i], 0, 0, 0);
    }

    // p = 2^(st + bias); pack 4 consecutive t -> one ds_write_b64
    #pragma unroll
    for (int i = 0; i < 2; ++i) {
      float rs = 0.f;
      #pragma unroll
      for (int ta = 0; ta < 4; ++ta) {
        float p0 = __builtin_amdgcn_exp2f(st[ta][i][0] + (float)bld[i][ta][0]);
        float p1 = __builtin_amdgcn_exp2f(st[ta][i][1] + (float)bld[i][ta][1]);
        float p2 = __builtin_amdgcn_exp2f(st[ta][i][2] + (float)bld[i][ta][2]);
        float p3 = __builtin_amdgcn_exp2f(st[ta][i][3] + (float)bld[i][ta][3]);
        rs += (p0 + p1) + (p2 + p3);
        short4 pk;
        pk.x = f2bf_fast(p0); pk.y = f2bf_fast(p1);
        pk.z = f2bf_fast(p2); pk.w = f2bf_fast(p3);
        *(short4*)&Ps[(w * 32 + i * 16 + ln) * 72 + ta * 16 + quad * 4] = pk;
      }
      rs += __shfl_xor(rs, 16);
      rs += __shfl_xor(rs, 32);
      l_st[i] += rs;
    }

    // O += P.V  (Ps rows wave-private; same-wave LDS ordering suffices)
    #pragma unroll
    for (int kk = 0; kk < 2; ++kk) {
      s16x8 pa[2], vbf[4];
      #pragma unroll
      for (int i = 0; i < 2; ++i)
        pa[i] = *(const s16x8*)&Ps[(w * 32 + i * 16 + ln) * 72 + kk * 32 + quad * 8];
      #pragma unroll
      for (int nt = 0; nt < 4; ++nt)
        vbf[nt] = *(const s16x8*)&Vs[b][((nt * 16 + ln) << 6) + (((kk * 4 + quad) ^ (ln & 7)) << 3)];
      #pragma unroll
      for (int i = 0; i < 2; ++i)
        #pragma unroll
        for (int nt = 0; nt < 4; ++nt)
          o[i][nt] = __builtin_amdgcn_mfma_f32_16x16x32_bf16(pa[i], vbf[nt], o[i][nt], 0, 0, 0);
    }
  }

  // epilogue: O / l -> concat. l for q-row quad*4+r lives at lane (..)|q-row.
  #pragma unroll
  for (int i = 0; i < 2; ++i) {
    float inv[4];
    #pragma unroll
    for (int r = 0; r < 4; ++r) {
      float lv = __shfl(l_st[i], (lane & 48) | (quad * 4 + r));
      inv[r] = __builtin_amdgcn_rcpf(lv);
    }
    long rowb = (long)bb * 2048 + q0 + w * 32 + i * 16 + quad * 4;
    #pragma unroll
    for (int nt = 0; nt < 4; ++nt)
      #pragma unroll
      for (int r = 0; r < 4; ++r)
        concat[(rowb + r) * 1024 + h * 64 + nt * 16 + ln] = f2bf(o[i][nt][r] * inv[r]);
  }
}

// ---------------------------------------------------------------------------
// Output GEMM (unchanged from R4).
// ---------------------------------------------------------------------------
__global__ __launch_bounds__(256, 3) void out_gemm(
    const short* __restrict__ A, const short* __restrict__ Bt,
    const float* __restrict__ bo, float* __restrict__ Cout) {
  __shared__ short Asub[128 * 64];
  __shared__ short Bsub[128 * 64];
  const int tid = threadIdx.x;
  const int w = tid >> 6, lane = tid & 63, ln = lane & 15, quad = lane >> 4;
  const int row0 = blockIdx.x * 128, n0 = blockIdx.y * 128;
  const int wm = (w & 1) * 64, wn = (w >> 1) * 64;

  f32x4 acc[4][4];
  #pragma unroll
  for (int i = 0; i < 4; ++i)
    #pragma unroll
    for (int j = 0; j < 4; ++j) acc[i][j] = (f32x4){0.f, 0.f, 0.f, 0.f};

  for (int kt = 0; kt < 16; ++kt) {
    const int k0 = kt * 64;
    #pragma unroll
    for (int j = 0; j < 4; ++j) {
      int ci = (w * 4 + j) * 64 + lane;
      int r = ci >> 3, s = ci & 7, g = s ^ (r & 7);
      const short* ga = A + (long)(row0 + r) * 1024 + k0 + g * 8;
      __builtin_amdgcn_global_load_lds(GA(ga), LA(&Asub[ci * 8]), 16, 0, 0);
      const short* gb = Bt + (long)(n0 + r) * 1024 + k0 + g * 8;
      __builtin_amdgcn_global_load_lds(GA(gb), LA(&Bsub[ci * 8]), 16, 0, 0);
    }
    __syncthreads();
    #pragma unroll
    for (int kk = 0; kk < 2; ++kk) {
      s16x8 af[4], bfr[4];
      #pragma unroll
      for (int i = 0; i < 4; ++i) {
        int ra = wm + i * 16 + ln;
        int slot = (kk * 4 + quad) ^ (ra & 7);
        af[i] = *(const s16x8*)&Asub[ra * 64 + slot * 8];
      }
      #pragma unroll
      for (int j = 0; j < 4; ++j) {
        int rb = wn + j * 16 + ln;
        int slot = (kk * 4 + quad) ^ (rb & 7);
        bfr[j] = *(const s16x8*)&Bsub[rb * 64 + slot * 8];
      }
      #pragma unroll
      for (int i = 0; i < 4; ++i)
        #pragma unroll
        for (int j = 0; j < 4; ++j)
          acc[i][j] = __builtin_amdgcn_mfma_f32_16x16x32_bf16(af[i], bfr[j], acc[i][j], 0, 0, 0);
    }
    __syncthreads();
  }
  #pragma unroll
  for (int j = 0; j < 4; ++j) {
    int n = n0 + wn + j * 16 + ln;
    float bvj = bo[n];
    #pragma unroll
    for (int i = 0; i < 4; ++i)
      #pragma unroll
      for (int r = 0; r < 4; ++r) {
        int row = row0 + wm + i * 16 + quad * 4 + r;
        Cout[(long)row * 1024 + n] = acc[i][j][r] + bvj;
      }
  }
}

// ---------------------------------------------------------------------------
// ws layout (72 MB total, proven budget):
//   [ 0, 8M)  WqkvT bf16 (6MB) -> overwritten by biasF16 fp16 (8MB) after proj
//   [ 8,40M)  qk bf16 (8192 x 2048)
//   [40,56M)  VT bf16 [(b,h,d) x t] -> WoT bf16 (2MB) overwrites after flash
//   [56,72M)  concat bf16 (8192 x 1024)
// ---------------------------------------------------------------------------
extern "C" void kernel_launch(void* const* d_in, const int* in_sizes, int n_in,
                              void* d_out, int out_size, void* d_ws, size_t ws_size,
                              hipStream_t stream) {
  const float* query = (const float*)d_in[0];
  const float* key_  = (const float*)d_in[1];
  const float* value = (const float*)d_in[2];
  const float* abias = (const float*)d_in[3];
  const float* Wq = (const float*)d_in[4];
  const float* bq = (const float*)d_in[5];
  const float* Wk = (const float*)d_in[6];
  const float* bk = (const float*)d_in[7];
  const float* Wv = (const float*)d_in[8];
  const float* bv = (const float*)d_in[9];
  const float* Wo = (const float*)d_in[10];
  const float* bo = (const float*)d_in[11];
  float* out = (float*)d_out;

  char* ws = (char*)d_ws;
  short*    WqkvT  = (short*)(ws);
  _Float16* biasF  = (_Float16*)(ws);
  short*    qk     = (short*)(ws + 8388608);
  short*    VT     = (short*)(ws + 41943040);
  short*    WoT    = (short*)(ws + 41943040);
  short*    concat = (short*)(ws + 58720256);

  dim3 tb(32, 8);
  transpose_qkv<<<dim3(2, 32, 48), tb, 0, stream>>>(Wq, Wk, Wv, WqkvT);
  proj_gemm<<<dim3(64, 24), 256, 0, stream>>>(query, key_, value, WqkvT, bq, bk, bv, qk, VT);
  bias_cast<<<dim3(4096), 256, 0, stream>>>(abias, biasF);
  flash_attn<<<dim3(16, 16, 4), 256, 0, stream>>>(qk, VT, biasF, concat);
  transpose_cast<<<dim3(32, 32, 1), tb, 0, stream>>>(Wo, WoT, 1024, 1024, 0L, 0L, 1.0f);
  out_gemm<<<dim3(64, 8), 256, 0, stream>>>(concat, WoT, bo, out);
}